// Round 14
// baseline (1439.232 us; speedup 1.0000x reference)
//
#include <hip/hip_runtime.h>
#include <math.h>

#define N_NODES 100000
#define N_EDGES 1600000
#define HDIM 128
#define NBLK 16
#define NREL 200
#define NW_AGG 8192  // balanced waves

typedef unsigned short ushort_t;
typedef unsigned int uint_t;
typedef _Float16 h2 __attribute__((ext_vector_type(2)));

__device__ __forceinline__ ushort_t f2h(float f) {
  _Float16 h = (_Float16)f;
  return __builtin_bit_cast(unsigned short, h);
}
__device__ __forceinline__ float h2f(ushort_t b) {
  return (float)__builtin_bit_cast(_Float16, b);
}

// acc += a.lo*b.lo + a.hi*b.hi  (packed f16 pairs, f32 accumulate)
#if defined(__has_builtin) && __has_builtin(__builtin_amdgcn_fdot2)
#define FDOT2(accv, au, bu)                                                    \
  accv = __builtin_amdgcn_fdot2(__builtin_bit_cast(h2, au),                    \
                                __builtin_bit_cast(h2, bu), accv, false);
#else
#define FDOT2(accv, au, bu)                                                    \
  {                                                                            \
    h2 av_ = __builtin_bit_cast(h2, au);                                       \
    h2 bv_ = __builtin_bit_cast(h2, bu);                                       \
    accv = fmaf((float)av_[0], (float)bv_[0], accv);                           \
    accv = fmaf((float)av_[1], (float)bv_[1], accv);                           \
  }
#endif

#if defined(__has_builtin) && __has_builtin(__builtin_amdgcn_global_load_lds)
#define HAVE_GLL 1
#else
#define HAVE_GLL 0
#endif

// Stage 16 h-rows (256B each, 4KB) into SLABP (wave-private LDS slab).
// Instr i in [0,4): lane l fetches 16B of row (i*4 + l/16) at byte (l&15)*16;
// LDS dest is lane-linear (base + l*16), region i at SLABP[i*512 ushorts].
#if HAVE_GLL
#define STAGE16(HSRC, SLABP, R, MM)                                            \
  {                                                                            \
    _Pragma("unroll") for (int i_ = 0; i_ < 4; ++i_) {                         \
      int ei_ = (i_ << 2) + (l >> 4);                                          \
      if (ei_ >= MM) ei_ = MM - 1;                                             \
      int ss_ = __shfl(R.x, ei_);                                              \
      const ushort_t* gsrc_ = HSRC + ((long)ss_ << 7) + ((l & 15) << 3);       \
      __builtin_amdgcn_global_load_lds(                                        \
          (const __attribute__((address_space(1))) unsigned int*)gsrc_,        \
          (__attribute__((address_space(3))) unsigned int*)&SLABP[i_ << 9],    \
          16, 0, 0);                                                           \
    }                                                                          \
  }
#define WAIT_STAGE asm volatile("s_waitcnt vmcnt(5)" ::: "memory");
#define WAIT_STAGE0 asm volatile("s_waitcnt vmcnt(0)" ::: "memory");
#else
#define STAGE16(HSRC, SLABP, R, MM)                                            \
  {                                                                            \
    _Pragma("unroll") for (int i_ = 0; i_ < 4; ++i_) {                         \
      int ei_ = (i_ << 2) + (l >> 4);                                          \
      if (ei_ >= MM) ei_ = MM - 1;                                             \
      int ss_ = __shfl(R.x, ei_);                                              \
      const ushort_t* gsrc_ = HSRC + ((long)ss_ << 7) + ((l & 15) << 3);       \
      uint4 t_ = *(const uint4*)gsrc_;                                         \
      *(uint4*)&SLABP[(i_ << 9) + (l << 3)] = t_;                              \
    }                                                                          \
  }
#define WAIT_STAGE
#define WAIT_STAGE0
#endif

// ================= CSR build (dst -> packed edge records) =================
__global__ __launch_bounds__(256) void hist_deg(const int* __restrict__ dst,
                                                int* __restrict__ deg) {
  int e = blockIdx.x * 256 + threadIdx.x;
  if (e < N_EDGES) atomicAdd(&deg[dst[e]], 1);
}

// exclusive scan; also writes offsets[N_NODES] = E
__global__ __launch_bounds__(1024) void scan_offsets(const int* __restrict__ deg,
                                                     int* __restrict__ offsets) {
  __shared__ int wsum[16];
  __shared__ int carry_s;
  int tid = threadIdx.x, lane = tid & 63, wid = tid >> 6;
  if (tid == 0) carry_s = 0;
  __syncthreads();
  for (int base = 0; base < N_NODES; base += 1024) {
    int i = base + tid;
    int v = (i < N_NODES) ? deg[i] : 0;
    int x = v;
#pragma unroll
    for (int s = 1; s < 64; s <<= 1) {
      int t = __shfl_up(x, s);
      if (lane >= s) x += t;
    }
    if (lane == 63) wsum[wid] = x;
    __syncthreads();
    if (wid == 0) {
      int y = (lane < 16) ? wsum[lane] : 0;
#pragma unroll
      for (int s = 1; s < 16; s <<= 1) {
        int t = __shfl_up(y, s);
        if (lane >= s) y += t;
      }
      if (lane < 16) wsum[lane] = y;
    }
    __syncthreads();
    int carry = carry_s;
    int wbase = (wid > 0) ? wsum[wid - 1] : 0;
    if (i < N_NODES) offsets[i] = carry + wbase + (x - v);
    __syncthreads();
    if (tid == 0) carry_s = carry + wsum[15];
    __syncthreads();
  }
  if (tid == 0) offsets[N_NODES] = carry_s;  // == N_EDGES
}

__global__ __launch_bounds__(256) void scatter_rec(
    const int* __restrict__ src, const int* __restrict__ dst,
    const int* __restrict__ etype, const float* __restrict__ norm,
    const int* __restrict__ offsets, int* __restrict__ cursor,
    int4* __restrict__ rec) {
  int e = blockIdx.x * 256 + threadIdx.x;
  if (e >= N_EDGES) return;
  int d = dst[e];
  int pos = offsets[d] + atomicAdd(&cursor[d], 1);
  rec[pos] = make_int4(src[e], etype[e], __float_as_int(norm[e]), 0);
}

// wave w owns nodes [ranges[w], ranges[w+1])
__global__ __launch_bounds__(256) void calc_ranges(const int* __restrict__ offsets,
                                                   int* __restrict__ ranges) {
  int w = blockIdx.x * 256 + threadIdx.x;
  if (w > NW_AGG) return;
  if (w == NW_AGG) {
    ranges[w] = N_NODES;
    return;
  }
  long t = ((long)w * N_EDGES + NW_AGG - 1) / NW_AGG;  // ceil(w*E/NW)
  int lo = 0, hi = N_NODES;
  while (lo < hi) {
    int mid = (lo + hi) >> 1;
    if ((long)offsets[mid] >= t) hi = mid;
    else lo = mid + 1;
  }
  ranges[w] = lo;
}

// f16 copy of gathered embeddings
__global__ __launch_bounds__(256) void conv_h0(const int* __restrict__ node_ids,
                                               const float* __restrict__ emb,
                                               ushort_t* __restrict__ h0h) {
  long gid = (long)blockIdx.x * 256 + threadIdx.x;
  if (gid >= (long)N_NODES * HDIM) return;
  int n = (int)(gid >> 7);
  int o = (int)(gid & 127);
  h0h[gid] = f2h(emb[(long)node_ids[n] * HDIM + o]);
}

// W1 (R,NB,8,8) fp32 -> Wh1 [rb][g(4)][c(2)][ip(4)][hi(2)] f16 (i = ip*2+hi, o = g*2+c)
__global__ __launch_bounds__(256) void conv_w1(const float* __restrict__ W,
                                               ushort_t* __restrict__ Wh) {
  int idx = blockIdx.x * 256 + threadIdx.x;
  if (idx >= NREL * NBLK * 64) return;
  int rb = idx >> 6, i = (idx >> 3) & 7, o = idx & 7;
  int g = o >> 1, c = o & 1, ip = i >> 1, hi = i & 1;
  Wh[(((rb * 4 + g) * 2 + c) * 4 + ip) * 2 + hi] = f2h(W[idx]);
}

// W2 (R,NB,8,16) fp32 -> Wh2 [rb][g(4)][c(4)][ip(4)][hi(2)] f16 (i = ip*2+hi, o = g*4+c)
__global__ __launch_bounds__(256) void conv_w2(const float* __restrict__ W,
                                               ushort_t* __restrict__ Wh) {
  int idx = blockIdx.x * 256 + threadIdx.x;
  if (idx >= NREL * NBLK * 128) return;
  int rb = idx >> 7, i = (idx >> 4) & 7, o = idx & 15;
  int g = o >> 2, c = o & 3, ip = i >> 1, hi = i & 1;
  Wh[(((rb * 4 + g) * 4 + c) * 4 + ip) * 2 + hi] = f2h(W[idx]);
}

// ================= Layer-1 aggregation: dbuf LDS h + W ping-pong ===========
__global__ __launch_bounds__(256, 4) void agg_layer1(
    const int4* __restrict__ rec, const int* __restrict__ offsets,
    const int* __restrict__ ranges, const ushort_t* __restrict__ h0h,
    const ushort_t* __restrict__ Wh, float* __restrict__ agg) {
  __shared__ __align__(16) ushort_t smem[4][2][2048];  // 2 x 4KB per wave
  int w = blockIdx.x * 4 + (threadIdx.x >> 6);
  int l = threadIdx.x & 63;
  int wid = threadIdx.x >> 6;
  int lo = ranges[w], hi = ranges[w + 1];
  if (lo >= hi) return;
  const ushort_t* Wl = Wh + (size_t)l * 16;
  int hoff = (l >> 2) << 3;
  int estart = offsets[lo];
  int ecnt = offsets[hi] - estart;
  int eend = estart + ecnt;
  int cur = lo;
  int next_b = offsets[lo + 1];
  int e = estart;
  float ac0 = 0.f, ac1 = 0.f;

#define L1_FLUSH                                                               \
  {                                                                            \
    float2 res = {ac0, ac1};                                                   \
    *(float2*)(agg + (long)cur * HDIM + (l << 1)) = res;                       \
    ac0 = ac1 = 0.f;                                                           \
    ++cur;                                                                     \
    next_b = offsets[cur + 1];                                                 \
  }

  if (ecnt > 0) {
    int4 rcur, rnxt;
    {
      int ix = estart + (l & 15);
      if (ix >= eend) ix = eend - 1;
      rcur = rec[ix];
    }
    {
      int ix = estart + 16 + (l & 15);
      if (ix >= eend) ix = eend - 1;
      rnxt = rec[ix];
    }
    {
      int m0 = ecnt < 16 ? ecnt : 16;
      ushort_t* slab0 = &smem[wid][0][0];
      STAGE16(h0h, slab0, rcur, m0)
    }
    WAIT_STAGE0
    int sl = 0;
    for (int c0 = 0; c0 < ecnt; c0 += 16) {
      int m = min(16, ecnt - c0);
      int4 rnew;
      {
        int ix = estart + c0 + 32 + (l & 15);
        if (ix >= eend) ix = eend - 1;
        rnew = rec[ix];
      }
      {
        int mn = ecnt - (c0 + 16);
        mn = mn < 1 ? 1 : (mn > 16 ? 16 : mn);
        ushort_t* slabn = &smem[wid][sl ^ 1][0];
        STAGE16(h0h, slabn, rnxt, mn)
      }
      WAIT_STAGE
      const ushort_t* slab = &smem[wid][sl][0];
      // W ping-pong compute
      uint4 A0, A1, B0, B1;
      {
        int wy0 = __shfl(rcur.y, 0);
        const uint4* Wq = (const uint4*)(Wl + (size_t)wy0 * 1024);
        A0 = Wq[0];
        A1 = Wq[1];
      }
      int k = 0;
#define L1_COMP(P0, P1, Q0, Q1)                                                \
      if (k + 1 < m) {                                                         \
        int wy2 = __shfl(rcur.y, k + 1);                                       \
        const uint4* Wq = (const uint4*)(Wl + (size_t)wy2 * 1024);             \
        Q0 = Wq[0];                                                            \
        Q1 = Wq[1];                                                            \
      }                                                                        \
      while (e == next_b) L1_FLUSH                                             \
      {                                                                        \
        float nn_ = __uint_as_float((uint_t)__shfl(rcur.z, k));                \
        uint4 u = *(const uint4*)&slab[(k << 7) + hoff];                       \
        float p0 = 0.f, p1 = 0.f;                                              \
        FDOT2(p0, u.x, P0.x) FDOT2(p0, u.y, P0.y)                              \
        FDOT2(p0, u.z, P0.z) FDOT2(p0, u.w, P0.w)                              \
        FDOT2(p1, u.x, P1.x) FDOT2(p1, u.y, P1.y)                              \
        FDOT2(p1, u.z, P1.z) FDOT2(p1, u.w, P1.w)                              \
        ac0 = fmaf(p0, nn_, ac0);                                              \
        ac1 = fmaf(p1, nn_, ac1);                                              \
      }                                                                        \
      ++e;                                                                     \
      if (++k >= m) break;

      while (true) {
        L1_COMP(A0, A1, B0, B1)
        L1_COMP(B0, B1, A0, A1)
      }
#undef L1_COMP
      rcur = rnxt;
      rnxt = rnew;
      sl ^= 1;
    }
  }
  // final flush: last node + trailing deg-0 nodes
  while (cur < hi) {
    float2 res = {ac0, ac1};
    *(float2*)(agg + (long)cur * HDIM + (l << 1)) = res;
    ac0 = ac1 = 0.f;
    ++cur;
  }
#undef L1_FLUSH
}

// ================= Layer-2 aggregation: dbuf LDS h + W ping-pong ===========
__global__ __launch_bounds__(256, 4) void agg_layer2(
    const int4* __restrict__ rec, const int* __restrict__ offsets,
    const int* __restrict__ ranges, const ushort_t* __restrict__ h1h,
    const ushort_t* __restrict__ Wh, float* __restrict__ agg) {
  __shared__ __align__(16) ushort_t smem[4][2][2048];  // 2 x 4KB per wave
  int w = blockIdx.x * 4 + (threadIdx.x >> 6);
  int l = threadIdx.x & 63;
  int wid = threadIdx.x >> 6;
  int lo = ranges[w], hi = ranges[w + 1];
  if (lo >= hi) return;
  const ushort_t* Wl = Wh + (size_t)l * 32;
  int hoff = (l >> 2) << 3;
  int estart = offsets[lo];
  int ecnt = offsets[hi] - estart;
  int eend = estart + ecnt;
  int cur = lo;
  int next_b = offsets[lo + 1];
  int e = estart;
  float ax = 0.f, ay = 0.f, az = 0.f, aw = 0.f;

#define L2_FLUSH                                                               \
  {                                                                            \
    float4 res = {ax, ay, az, aw};                                             \
    *(float4*)(agg + (long)cur * 256 + (l << 2)) = res;                        \
    ax = ay = az = aw = 0.f;                                                   \
    ++cur;                                                                     \
    next_b = offsets[cur + 1];                                                 \
  }

  if (ecnt > 0) {
    int4 rcur, rnxt;
    {
      int ix = estart + (l & 15);
      if (ix >= eend) ix = eend - 1;
      rcur = rec[ix];
    }
    {
      int ix = estart + 16 + (l & 15);
      if (ix >= eend) ix = eend - 1;
      rnxt = rec[ix];
    }
    {
      int m0 = ecnt < 16 ? ecnt : 16;
      ushort_t* slab0 = &smem[wid][0][0];
      STAGE16(h1h, slab0, rcur, m0)
    }
    WAIT_STAGE0
    int sl = 0;
    for (int c0 = 0; c0 < ecnt; c0 += 16) {
      int m = min(16, ecnt - c0);
      int4 rnew;
      {
        int ix = estart + c0 + 32 + (l & 15);
        if (ix >= eend) ix = eend - 1;
        rnew = rec[ix];
      }
      {
        int mn = ecnt - (c0 + 16);
        mn = mn < 1 ? 1 : (mn > 16 ? 16 : mn);
        ushort_t* slabn = &smem[wid][sl ^ 1][0];
        STAGE16(h1h, slabn, rnxt, mn)
      }
      WAIT_STAGE
      const ushort_t* slab = &smem[wid][sl][0];
      uint4 A0, A1, A2, A3, B0, B1, B2, B3;
      {
        int wy0 = __shfl(rcur.y, 0);
        const uint4* Wq = (const uint4*)(Wl + (size_t)wy0 * 2048);
        A0 = Wq[0];
        A1 = Wq[1];
        A2 = Wq[2];
        A3 = Wq[3];
      }
      int k = 0;
#define L2_COMP(P0, P1, P2, P3, Q0, Q1, Q2, Q3)                                \
      if (k + 1 < m) {                                                         \
        int wy2 = __shfl(rcur.y, k + 1);                                       \
        const uint4* Wq = (const uint4*)(Wl + (size_t)wy2 * 2048);             \
        Q0 = Wq[0];                                                            \
        Q1 = Wq[1];                                                            \
        Q2 = Wq[2];                                                            \
        Q3 = Wq[3];                                                            \
      }                                                                        \
      while (e == next_b) L2_FLUSH                                             \
      {                                                                        \
        float nn_ = __uint_as_float((uint_t)__shfl(rcur.z, k));                \
        uint4 u = *(const uint4*)&slab[(k << 7) + hoff];                       \
        float px = 0.f, py = 0.f, pz = 0.f, pw = 0.f;                          \
        FDOT2(px, u.x, P0.x) FDOT2(px, u.y, P0.y)                              \
        FDOT2(px, u.z, P0.z) FDOT2(px, u.w, P0.w)                              \
        FDOT2(py, u.x, P1.x) FDOT2(py, u.y, P1.y)                              \
        FDOT2(py, u.z, P1.z) FDOT2(py, u.w, P1.w)                              \
        FDOT2(pz, u.x, P2.x) FDOT2(pz, u.y, P2.y)                              \
        FDOT2(pz, u.z, P2.z) FDOT2(pz, u.w, P2.w)                              \
        FDOT2(pw, u.x, P3.x) FDOT2(pw, u.y, P3.y)                              \
        FDOT2(pw, u.z, P3.z) FDOT2(pw, u.w, P3.w)                              \
        ax = fmaf(px, nn_, ax);                                                \
        ay = fmaf(py, nn_, ay);                                                \
        az = fmaf(pz, nn_, az);                                                \
        aw = fmaf(pw, nn_, aw);                                                \
      }                                                                        \
      ++e;                                                                     \
      if (++k >= m) break;

      while (true) {
        L2_COMP(A0, A1, A2, A3, B0, B1, B2, B3)
        L2_COMP(B0, B1, B2, B3, A0, A1, A2, A3)
      }
#undef L2_COMP
      rcur = rnxt;
      rnxt = rnew;
      sl ^= 1;
    }
  }
  while (cur < hi) {
    float4 res = {ax, ay, az, aw};
    *(float4*)(agg + (long)cur * 256 + (l << 2)) = res;
    ax = ay = az = aw = 0.f;
    ++cur;
  }
#undef L2_FLUSH
}

// ================= Node kernels (dense self-loop + epilogue) =================
__global__ __launch_bounds__(256) void node_layer1(
    const int* __restrict__ node_ids, const float* __restrict__ emb,
    const float* __restrict__ loop1, const float* __restrict__ agg1,
    const float* __restrict__ bias, ushort_t* __restrict__ h1h) {
  __shared__ float L[HDIM * HDIM];
  __shared__ float hs[2][HDIM];
  for (int idx = threadIdx.x; idx < HDIM * HDIM; idx += 256) L[idx] = loop1[idx];
  __syncthreads();
  int o = threadIdx.x & 127;
  int sub = threadIdx.x >> 7;
  for (int base = blockIdx.x * 2; base < N_NODES; base += gridDim.x * 2) {
    int n = base + sub;
    if (n < N_NODES) hs[sub][o] = emb[(long)node_ids[n] * HDIM + o];
    __syncthreads();
    if (n < N_NODES) {
      float acc = 0.f;
#pragma unroll
      for (int i = 0; i < HDIM; ++i) acc = fmaf(hs[sub][i], L[i * HDIM + o], acc);
      float v = acc + bias[o] + agg1[(long)n * HDIM + o];
      h1h[(long)n * HDIM + o] = f2h(fmaxf(v, 0.f));
    }
    __syncthreads();
  }
}

__global__ __launch_bounds__(256) void node_layer2a(
    const ushort_t* __restrict__ h1h, const float* __restrict__ loop2,
    const float* __restrict__ agg2, const float* __restrict__ bias2,
    float* __restrict__ outm) {
  __shared__ float L[HDIM * HDIM];
  __shared__ float hs[2][HDIM];
  for (int idx = threadIdx.x; idx < HDIM * HDIM; idx += 256) {
    int i = idx >> 7, oo = idx & 127;
    L[idx] = loop2[i * 256 + oo];
  }
  __syncthreads();
  int o = threadIdx.x & 127;
  int sub = threadIdx.x >> 7;
  for (int base = blockIdx.x * 2; base < N_NODES; base += gridDim.x * 2) {
    int n = base + sub;
    if (n < N_NODES) hs[sub][o] = h2f(h1h[(long)n * HDIM + o]);
    __syncthreads();
    if (n < N_NODES) {
      float acc = 0.f;
#pragma unroll
      for (int i = 0; i < HDIM; ++i) acc = fmaf(hs[sub][i], L[i * HDIM + o], acc);
      outm[(long)n * HDIM + o] = acc + bias2[o] + agg2[(long)n * 256 + o];
    }
    __syncthreads();
  }
}

__global__ __launch_bounds__(256) void node_layer2b(
    const ushort_t* __restrict__ h1h, const float* __restrict__ loop2,
    const float* __restrict__ agg2, const float* __restrict__ bias2,
    const float* __restrict__ eps, float* __restrict__ out) {
  __shared__ float L[HDIM * HDIM];
  __shared__ float hs[2][HDIM];
  for (int idx = threadIdx.x; idx < HDIM * HDIM; idx += 256) {
    int i = idx >> 7, oo = idx & 127;
    L[idx] = loop2[i * 256 + 128 + oo];
  }
  __syncthreads();
  int o = threadIdx.x & 127;
  int sub = threadIdx.x >> 7;
  for (int base = blockIdx.x * 2; base < N_NODES; base += gridDim.x * 2) {
    int n = base + sub;
    if (n < N_NODES) hs[sub][o] = h2f(h1h[(long)n * HDIM + o]);
    __syncthreads();
    if (n < N_NODES) {
      float acc = 0.f;
#pragma unroll
      for (int i = 0; i < HDIM; ++i) acc = fmaf(hs[sub][i], L[i * HDIM + o], acc);
      float hv = acc + bias2[128 + o] + agg2[(long)n * 256 + 128 + o];
      float sp = fmaxf(hv, 0.f) + log1pf(expf(-fabsf(hv)));
      float var = sp + 1e-8f;
      long off = (long)n * HDIM + o;
      out[off] = out[off] + sqrtf(var) * eps[off];
    }
    __syncthreads();
  }
}

extern "C" void kernel_launch(void* const* d_in, const int* in_sizes, int n_in,
                              void* d_out, int out_size, void* d_ws, size_t ws_size,
                              hipStream_t stream) {
  const int* node_ids = (const int*)d_in[0];
  const int* src      = (const int*)d_in[1];
  const int* dst      = (const int*)d_in[2];
  const int* etype    = (const int*)d_in[3];
  const float* norm   = (const float*)d_in[4];
  const float* emb    = (const float*)d_in[5];
  const float* W1     = (const float*)d_in[6];
  const float* loop1  = (const float*)d_in[7];
  const float* b1     = (const float*)d_in[8];
  const float* W2     = (const float*)d_in[9];
  const float* loop2  = (const float*)d_in[10];
  const float* b2     = (const float*)d_in[11];
  const float* eps    = (const float*)d_in[12];
  float* out = (float*)d_out;

  char* ws = (char*)d_ws;
  size_t off = 0;
  int* deg       = (int*)(ws + off); off += (size_t)N_NODES * 4;
  int* offsets   = (int*)(ws + off); off += (size_t)(N_NODES + 1) * 4;
  int* cursor    = (int*)(ws + off); off += (size_t)N_NODES * 4;
  int* ranges    = (int*)(ws + off); off += (size_t)(NW_AGG + 1) * 4;
  int4* rec      = (int4*)(ws + off); off += (size_t)N_EDGES * 16;
  float* agg2    = (float*)(ws + off); off += (size_t)N_NODES * 256 * 4;
  ushort_t* h0h  = (ushort_t*)(ws + off); off += (size_t)N_NODES * HDIM * 2;
  ushort_t* h1h  = (ushort_t*)(ws + off); off += (size_t)N_NODES * HDIM * 2;
  ushort_t* Wh1  = (ushort_t*)(ws + off); off += (size_t)NREL * NBLK * 64 * 2;
  ushort_t* Wh2  = (ushort_t*)(ws + off); off += (size_t)NREL * NBLK * 128 * 2;
  float* agg1 = out;  // agg1 lives in d_out (dead before node_layer2a writes)

  // ---- CSR build + f16 conversions ----
  hipMemsetAsync(deg, 0, (size_t)N_NODES * 4, stream);
  hipMemsetAsync(cursor, 0, (size_t)N_NODES * 4, stream);
  hist_deg<<<(N_EDGES + 255) / 256, 256, 0, stream>>>(dst, deg);
  conv_w1<<<(NREL * NBLK * 64 + 255) / 256, 256, 0, stream>>>(W1, Wh1);
  conv_w2<<<(NREL * NBLK * 128 + 255) / 256, 256, 0, stream>>>(W2, Wh2);
  scan_offsets<<<1, 1024, 0, stream>>>(deg, offsets);
  calc_ranges<<<(NW_AGG + 256) / 256, 256, 0, stream>>>(offsets, ranges);
  scatter_rec<<<(N_EDGES + 255) / 256, 256, 0, stream>>>(src, dst, etype, norm,
                                                         offsets, cursor, rec);
  conv_h0<<<(N_NODES * HDIM + 255) / 256, 256, 0, stream>>>(node_ids, emb, h0h);

  // ---- layer 1 ----
  agg_layer1<<<NW_AGG / 4, 256, 0, stream>>>(rec, offsets, ranges, h0h, Wh1, agg1);
  node_layer1<<<512, 256, 0, stream>>>(node_ids, emb, loop1, agg1, b1, h1h);

  // ---- layer 2 ----
  agg_layer2<<<NW_AGG / 4, 256, 0, stream>>>(rec, offsets, ranges, h1h, Wh2, agg2);
  node_layer2a<<<512, 256, 0, stream>>>(h1h, loop2, agg2, b2, out);
  node_layer2b<<<512, 256, 0, stream>>>(h1h, loop2, agg2, b2, eps, out);
}

// Round 15
// 1150.920 us; speedup vs baseline: 1.2505x; 1.2505x over previous
//
#include <hip/hip_runtime.h>
#include <math.h>

#define N_NODES 100000
#define N_EDGES 1600000
#define HDIM 128
#define NBLK 16
#define NREL 200
#define NW_AGG 8192  // balanced waves
#define NT 8         // node-tile for node kernels

typedef unsigned short ushort_t;
typedef unsigned int uint_t;
typedef _Float16 h2 __attribute__((ext_vector_type(2)));

__device__ __forceinline__ ushort_t f2h(float f) {
  _Float16 h = (_Float16)f;
  return __builtin_bit_cast(unsigned short, h);
}
__device__ __forceinline__ float h2f(ushort_t b) {
  return (float)__builtin_bit_cast(_Float16, b);
}

// acc += a.lo*b.lo + a.hi*b.hi  (packed f16 pairs, f32 accumulate)
#if defined(__has_builtin) && __has_builtin(__builtin_amdgcn_fdot2)
#define FDOT2(accv, au, bu)                                                    \
  accv = __builtin_amdgcn_fdot2(__builtin_bit_cast(h2, au),                    \
                                __builtin_bit_cast(h2, bu), accv, false);
#else
#define FDOT2(accv, au, bu)                                                    \
  {                                                                            \
    h2 av_ = __builtin_bit_cast(h2, au);                                       \
    h2 bv_ = __builtin_bit_cast(h2, bu);                                       \
    accv = fmaf((float)av_[0], (float)bv_[0], accv);                           \
    accv = fmaf((float)av_[1], (float)bv_[1], accv);                           \
  }
#endif

#if defined(__has_builtin) && __has_builtin(__builtin_amdgcn_global_load_lds)
#define HAVE_GLL 1
#else
#define HAVE_GLL 0
#endif

// Stage 32 h-rows (256B each, 8KB total) of the current chunk into this
// wave's LDS slab. Instr i: lane l fetches 16B at row (i*4 + l/16),
// byte-offset (l&15)*16; LDS dest is lane-linear (base + l*16).
#if HAVE_GLL
#define STAGE_H(HSRC, SMEMW)                                                   \
  {                                                                            \
    _Pragma("unroll") for (int i_ = 0; i_ < 8; ++i_) {                         \
      int ei_ = (i_ << 2) + (l >> 4);                                          \
      if (ei_ >= m) ei_ = m - 1;                                               \
      int ss_ = __shfl(r.x, ei_);                                              \
      const ushort_t* gsrc_ = HSRC + ((long)ss_ << 7) + ((l & 15) << 3);       \
      __builtin_amdgcn_global_load_lds(                                        \
          (const __attribute__((address_space(1))) unsigned int*)gsrc_,        \
          (__attribute__((address_space(3))) unsigned int*)&SMEMW[i_ << 9],    \
          16, 0, 0);                                                           \
    }                                                                          \
    asm volatile("s_waitcnt vmcnt(0)" ::: "memory");                           \
  }
#else
#define STAGE_H(HSRC, SMEMW)                                                   \
  {                                                                            \
    _Pragma("unroll") for (int i_ = 0; i_ < 8; ++i_) {                         \
      int ei_ = (i_ << 2) + (l >> 4);                                          \
      if (ei_ >= m) ei_ = m - 1;                                               \
      int ss_ = __shfl(r.x, ei_);                                              \
      const ushort_t* gsrc_ = HSRC + ((long)ss_ << 7) + ((l & 15) << 3);       \
      uint4 t_ = *(const uint4*)gsrc_;                                         \
      *(uint4*)&SMEMW[(i_ << 9) + (l << 3)] = t_;                              \
    }                                                                          \
  }
#endif

// ================= CSR build (dst -> packed edge records) =================
__global__ __launch_bounds__(256) void hist_deg(const int* __restrict__ dst,
                                                int* __restrict__ deg) {
  int e = blockIdx.x * 256 + threadIdx.x;
  if (e < N_EDGES) atomicAdd(&deg[dst[e]], 1);
}

// exclusive scan; also writes offsets[N_NODES] = E
__global__ __launch_bounds__(1024) void scan_offsets(const int* __restrict__ deg,
                                                     int* __restrict__ offsets) {
  __shared__ int wsum[16];
  __shared__ int carry_s;
  int tid = threadIdx.x, lane = tid & 63, wid = tid >> 6;
  if (tid == 0) carry_s = 0;
  __syncthreads();
  for (int base = 0; base < N_NODES; base += 1024) {
    int i = base + tid;
    int v = (i < N_NODES) ? deg[i] : 0;
    int x = v;
#pragma unroll
    for (int s = 1; s < 64; s <<= 1) {
      int t = __shfl_up(x, s);
      if (lane >= s) x += t;
    }
    if (lane == 63) wsum[wid] = x;
    __syncthreads();
    if (wid == 0) {
      int y = (lane < 16) ? wsum[lane] : 0;
#pragma unroll
      for (int s = 1; s < 16; s <<= 1) {
        int t = __shfl_up(y, s);
        if (lane >= s) y += t;
      }
      if (lane < 16) wsum[lane] = y;
    }
    __syncthreads();
    int carry = carry_s;
    int wbase = (wid > 0) ? wsum[wid - 1] : 0;
    if (i < N_NODES) offsets[i] = carry + wbase + (x - v);
    __syncthreads();
    if (tid == 0) carry_s = carry + wsum[15];
    __syncthreads();
  }
  if (tid == 0) offsets[N_NODES] = carry_s;  // == N_EDGES
}

__global__ __launch_bounds__(256) void scatter_rec(
    const int* __restrict__ src, const int* __restrict__ dst,
    const int* __restrict__ etype, const float* __restrict__ norm,
    const int* __restrict__ offsets, int* __restrict__ cursor,
    int4* __restrict__ rec) {
  int e = blockIdx.x * 256 + threadIdx.x;
  if (e >= N_EDGES) return;
  int d = dst[e];
  int pos = offsets[d] + atomicAdd(&cursor[d], 1);
  rec[pos] = make_int4(src[e], etype[e], __float_as_int(norm[e]), 0);
}

// wave w owns nodes [ranges[w], ranges[w+1])
__global__ __launch_bounds__(256) void calc_ranges(const int* __restrict__ offsets,
                                                   int* __restrict__ ranges) {
  int w = blockIdx.x * 256 + threadIdx.x;
  if (w > NW_AGG) return;
  if (w == NW_AGG) {
    ranges[w] = N_NODES;
    return;
  }
  long t = ((long)w * N_EDGES + NW_AGG - 1) / NW_AGG;  // ceil(w*E/NW)
  int lo = 0, hi = N_NODES;
  while (lo < hi) {
    int mid = (lo + hi) >> 1;
    if ((long)offsets[mid] >= t) hi = mid;
    else lo = mid + 1;
  }
  ranges[w] = lo;
}

// f16 copy of gathered embeddings
__global__ __launch_bounds__(256) void conv_h0(const int* __restrict__ node_ids,
                                               const float* __restrict__ emb,
                                               ushort_t* __restrict__ h0h) {
  long gid = (long)blockIdx.x * 256 + threadIdx.x;
  if (gid >= (long)N_NODES * HDIM) return;
  int n = (int)(gid >> 7);
  int o = (int)(gid & 127);
  h0h[gid] = f2h(emb[(long)node_ids[n] * HDIM + o]);
}

// W1 (R,NB,8,8) fp32 -> Wh1 [rb][g(4)][c(2)][ip(4)][hi(2)] f16 (i = ip*2+hi, o = g*2+c)
__global__ __launch_bounds__(256) void conv_w1(const float* __restrict__ W,
                                               ushort_t* __restrict__ Wh) {
  int idx = blockIdx.x * 256 + threadIdx.x;
  if (idx >= NREL * NBLK * 64) return;
  int rb = idx >> 6, i = (idx >> 3) & 7, o = idx & 7;
  int g = o >> 1, c = o & 1, ip = i >> 1, hi = i & 1;
  Wh[(((rb * 4 + g) * 2 + c) * 4 + ip) * 2 + hi] = f2h(W[idx]);
}

// W2 (R,NB,8,16) fp32 -> Wh2 [rb][g(4)][c(4)][ip(4)][hi(2)] f16 (i = ip*2+hi, o = g*4+c)
__global__ __launch_bounds__(256) void conv_w2(const float* __restrict__ W,
                                               ushort_t* __restrict__ Wh) {
  int idx = blockIdx.x * 256 + threadIdx.x;
  if (idx >= NREL * NBLK * 128) return;
  int rb = idx >> 7, i = (idx >> 4) & 7, o = idx & 15;
  int g = o >> 2, c = o & 3, ip = i >> 1, hi = i & 1;
  Wh[(((rb * 4 + g) * 4 + c) * 4 + ip) * 2 + hi] = f2h(W[idx]);
}

// ================= Layer-1 aggregation: LDS-staged h, balanced waves =======
__global__ __launch_bounds__(256, 4) void agg_layer1(
    const int4* __restrict__ rec, const int* __restrict__ offsets,
    const int* __restrict__ ranges, const ushort_t* __restrict__ h0h,
    const ushort_t* __restrict__ Wh, float* __restrict__ agg) {
  __shared__ __align__(16) ushort_t smem[4][4096];  // 8KB per wave
  int w = blockIdx.x * 4 + (threadIdx.x >> 6);
  int l = threadIdx.x & 63;
  int wid = threadIdx.x >> 6;
  int lo = ranges[w], hi = ranges[w + 1];
  if (lo >= hi) return;
  const ushort_t* Wl = Wh + (size_t)l * 16;
  int hoff = (l >> 2) << 3;  // ushort offset of this lane's h segment in a row
  int estart = offsets[lo];
  int ecnt = offsets[hi] - estart;
  int cur = lo;
  int next_b = offsets[lo + 1];
  int e = estart;
  float ac0 = 0.f, ac1 = 0.f;

#define L1_FLUSH                                                               \
  {                                                                            \
    float2 res = {ac0, ac1};                                                   \
    *(float2*)(agg + (long)cur * HDIM + (l << 1)) = res;                       \
    ac0 = ac1 = 0.f;                                                           \
    ++cur;                                                                     \
    next_b = offsets[cur + 1];                                                 \
  }

  for (int c0 = 0; c0 < ecnt; c0 += 32) {
    int m = min(32, ecnt - c0);
    int4 r = make_int4(0, 0, 0, 0);
    if (l < m) r = rec[estart + c0 + l];
    STAGE_H(h0h, smem[wid])
    for (int k = 0; k < m; ++k) {
      while (e == next_b) L1_FLUSH
      int wy_ = __shfl(r.y, k);
      float nn_ = __uint_as_float((uint_t)__shfl(r.z, k));
      const uint4* Wp_ = (const uint4*)(Wl + (size_t)wy_ * 1024);
      uint4 q0_ = Wp_[0], q1_ = Wp_[1];
      uint4 u = *(const uint4*)&smem[wid][(k << 7) + hoff];
      float p0 = 0.f, p1 = 0.f;
      FDOT2(p0, u.x, q0_.x) FDOT2(p0, u.y, q0_.y)
      FDOT2(p0, u.z, q0_.z) FDOT2(p0, u.w, q0_.w)
      FDOT2(p1, u.x, q1_.x) FDOT2(p1, u.y, q1_.y)
      FDOT2(p1, u.z, q1_.z) FDOT2(p1, u.w, q1_.w)
      ac0 = fmaf(p0, nn_, ac0);
      ac1 = fmaf(p1, nn_, ac1);
      ++e;
    }
  }
  // final flush: last node + trailing deg-0 nodes
  while (cur < hi) {
    float2 res = {ac0, ac1};
    *(float2*)(agg + (long)cur * HDIM + (l << 1)) = res;
    ac0 = ac1 = 0.f;
    ++cur;
  }
#undef L1_FLUSH
}

// ================= Layer-2 aggregation: LDS-staged h, balanced waves =======
__global__ __launch_bounds__(256, 4) void agg_layer2(
    const int4* __restrict__ rec, const int* __restrict__ offsets,
    const int* __restrict__ ranges, const ushort_t* __restrict__ h1h,
    const ushort_t* __restrict__ Wh, float* __restrict__ agg) {
  __shared__ __align__(16) ushort_t smem[4][4096];  // 8KB per wave
  int w = blockIdx.x * 4 + (threadIdx.x >> 6);
  int l = threadIdx.x & 63;
  int wid = threadIdx.x >> 6;
  int lo = ranges[w], hi = ranges[w + 1];
  if (lo >= hi) return;
  const ushort_t* Wl = Wh + (size_t)l * 32;
  int hoff = (l >> 2) << 3;
  int estart = offsets[lo];
  int ecnt = offsets[hi] - estart;
  int cur = lo;
  int next_b = offsets[lo + 1];
  int e = estart;
  float ax = 0.f, ay = 0.f, az = 0.f, aw = 0.f;

#define L2_FLUSH                                                               \
  {                                                                            \
    float4 res = {ax, ay, az, aw};                                             \
    *(float4*)(agg + (long)cur * 256 + (l << 2)) = res;                        \
    ax = ay = az = aw = 0.f;                                                   \
    ++cur;                                                                     \
    next_b = offsets[cur + 1];                                                 \
  }

  for (int c0 = 0; c0 < ecnt; c0 += 32) {
    int m = min(32, ecnt - c0);
    int4 r = make_int4(0, 0, 0, 0);
    if (l < m) r = rec[estart + c0 + l];
    STAGE_H(h1h, smem[wid])
    for (int k = 0; k < m; ++k) {
      while (e == next_b) L2_FLUSH
      int wy_ = __shfl(r.y, k);
      float nn_ = __uint_as_float((uint_t)__shfl(r.z, k));
      const uint4* Wp_ = (const uint4*)(Wl + (size_t)wy_ * 2048);
      uint4 q0_ = Wp_[0], q1_ = Wp_[1], q2_ = Wp_[2], q3_ = Wp_[3];
      uint4 u = *(const uint4*)&smem[wid][(k << 7) + hoff];
      float px = 0.f, py = 0.f, pz = 0.f, pw = 0.f;
      FDOT2(px, u.x, q0_.x) FDOT2(px, u.y, q0_.y)
      FDOT2(px, u.z, q0_.z) FDOT2(px, u.w, q0_.w)
      FDOT2(py, u.x, q1_.x) FDOT2(py, u.y, q1_.y)
      FDOT2(py, u.z, q1_.z) FDOT2(py, u.w, q1_.w)
      FDOT2(pz, u.x, q2_.x) FDOT2(pz, u.y, q2_.y)
      FDOT2(pz, u.z, q2_.z) FDOT2(pz, u.w, q2_.w)
      FDOT2(pw, u.x, q3_.x) FDOT2(pw, u.y, q3_.y)
      FDOT2(pw, u.z, q3_.z) FDOT2(pw, u.w, q3_.w)
      ax = fmaf(px, nn_, ax);
      ay = fmaf(py, nn_, ay);
      az = fmaf(pz, nn_, az);
      aw = fmaf(pw, nn_, aw);
      ++e;
    }
  }
  while (cur < hi) {
    float4 res = {ax, ay, az, aw};
    *(float4*)(agg + (long)cur * 256 + (l << 2)) = res;
    ax = ay = az = aw = 0.f;
    ++cur;
  }
#undef L2_FLUSH
}

// ========== Node layer 1: register-tiled (NT nodes/sweep), f16 L ==========
// h1[n][o] = relu(agg1[n][o] + b1[o] + sum_i h0[n][i]*loop1[i][o])
__global__ __launch_bounds__(256) void node_layer1(
    const ushort_t* __restrict__ h0h, const float* __restrict__ loop1,
    const float* __restrict__ agg1, const float* __restrict__ bias,
    ushort_t* __restrict__ h1h) {
  __shared__ __align__(8) ushort_t Lh[128 * 130];  // [o][i], pad 2
  __shared__ __align__(8) ushort_t hs[NT * 128];   // [j][i]
  int tid = threadIdx.x;
  // stage loop1 transposed to f16 [o][i]
  for (int t = 0; t < 64; ++t) {
    int flat = t * 256 + tid;  // 16384 elems
    int i = flat >> 7, o = flat & 127;
    Lh[o * 130 + i] = f2h(loop1[i * 128 + o]);
  }
  __syncthreads();
  int o = tid & 127;
  int g = tid >> 7;  // node group: 0 -> nodes 0..3, 1 -> nodes 4..7
  for (int grp = blockIdx.x; grp < N_NODES / NT; grp += gridDim.x) {
    int n0 = grp * NT;
    __syncthreads();
    for (int t = 0; t < 4; ++t) {
      int flat = t * 256 + tid;  // 1024 elems
      int j = flat >> 7, i = flat & 127;
      hs[j * 128 + i] = h0h[(long)(n0 + j) * 128 + i];
    }
    __syncthreads();
    float acc[4] = {0.f, 0.f, 0.f, 0.f};
    const ushort_t* Lo = &Lh[o * 130];
    const ushort_t* hb = &hs[(g * 4) * 128];
    for (int i = 0; i < 128; i += 4) {
      uint_t lv01 = *(const uint_t*)&Lo[i];
      uint_t lv23 = *(const uint_t*)&Lo[i + 2];
#pragma unroll
      for (int j = 0; j < 4; ++j) {
        uint2 hj = *(const uint2*)&hb[j * 128 + i];
        FDOT2(acc[j], hj.x, lv01)
        FDOT2(acc[j], hj.y, lv23)
      }
    }
    float bo = bias[o];
#pragma unroll
    for (int j = 0; j < 4; ++j) {
      int n = n0 + g * 4 + j;
      float v = acc[j] + bo + agg1[(long)n * 128 + o];
      h1h[(long)n * 128 + o] = f2h(fmaxf(v, 0.f));
    }
  }
}

// ========== Node layer 2 fused: m + hv + gaussian sample ==========
// col o<128 -> m; col o>=128 -> hv -> sp = sqrt(softplus+1e-8) via LDS;
// out = m + sp*eps
__global__ __launch_bounds__(256) void node_layer2f(
    const ushort_t* __restrict__ h1h, const float* __restrict__ loop2,
    const float* __restrict__ agg2, const float* __restrict__ bias2,
    const float* __restrict__ eps, float* __restrict__ out) {
  __shared__ __align__(8) ushort_t Lh[256 * 130];  // [c][i], pad 2 (65 KB)
  __shared__ __align__(8) ushort_t hs[NT * 128];   // [j][i] (2 KB)
  __shared__ float spbuf[NT * 128];                // (4 KB)
  int o = threadIdx.x;  // output column 0..255
  for (int t = 0; t < 128; ++t) {
    int flat = t * 256 + o;  // 32768 elems
    int i = flat >> 8, c = flat & 255;
    Lh[c * 130 + i] = f2h(loop2[i * 256 + c]);
  }
  __syncthreads();
  for (int grp = blockIdx.x; grp < N_NODES / NT; grp += gridDim.x) {
    int n0 = grp * NT;
    __syncthreads();
    for (int t = 0; t < 4; ++t) {
      int flat = t * 256 + o;  // 1024 elems
      int j = flat >> 7, i = flat & 127;
      hs[j * 128 + i] = h1h[(long)(n0 + j) * 128 + i];
    }
    __syncthreads();
    float acc[NT] = {0.f, 0.f, 0.f, 0.f, 0.f, 0.f, 0.f, 0.f};
    const ushort_t* Lo = &Lh[o * 130];
    for (int i = 0; i < 128; i += 4) {
      uint_t lv01 = *(const uint_t*)&Lo[i];
      uint_t lv23 = *(const uint_t*)&Lo[i + 2];
#pragma unroll
      for (int j = 0; j < NT; ++j) {
        uint2 hj = *(const uint2*)&hs[j * 128 + i];
        FDOT2(acc[j], hj.x, lv01)
        FDOT2(acc[j], hj.y, lv23)
      }
    }
    float bo = bias2[o];
    if (o >= 128) {
      int oc = o - 128;
#pragma unroll
      for (int j = 0; j < NT; ++j) {
        float hv = acc[j] + bo + agg2[(long)(n0 + j) * 256 + o];
        float sp = fmaxf(hv, 0.f) + log1pf(expf(-fabsf(hv)));
        spbuf[j * 128 + oc] = sqrtf(sp + 1e-8f);
      }
    }
    __syncthreads();
    if (o < 128) {
#pragma unroll
      for (int j = 0; j < NT; ++j) {
        float mval = acc[j] + bo + agg2[(long)(n0 + j) * 256 + o];
        long off2 = (long)(n0 + j) * 128 + o;
        out[off2] = mval + spbuf[j * 128 + o] * eps[off2];
      }
    }
  }
}

extern "C" void kernel_launch(void* const* d_in, const int* in_sizes, int n_in,
                              void* d_out, int out_size, void* d_ws, size_t ws_size,
                              hipStream_t stream) {
  const int* node_ids = (const int*)d_in[0];
  const int* src      = (const int*)d_in[1];
  const int* dst      = (const int*)d_in[2];
  const int* etype    = (const int*)d_in[3];
  const float* norm   = (const float*)d_in[4];
  const float* emb    = (const float*)d_in[5];
  const float* W1     = (const float*)d_in[6];
  const float* loop1  = (const float*)d_in[7];
  const float* b1     = (const float*)d_in[8];
  const float* W2     = (const float*)d_in[9];
  const float* loop2  = (const float*)d_in[10];
  const float* b2     = (const float*)d_in[11];
  const float* eps    = (const float*)d_in[12];
  float* out = (float*)d_out;

  char* ws = (char*)d_ws;
  size_t off = 0;
  int* deg       = (int*)(ws + off); off += (size_t)N_NODES * 4;
  int* offsets   = (int*)(ws + off); off += (size_t)(N_NODES + 1) * 4;
  int* cursor    = (int*)(ws + off); off += (size_t)N_NODES * 4;
  int* ranges    = (int*)(ws + off); off += (size_t)(NW_AGG + 1) * 4;
  int4* rec      = (int4*)(ws + off); off += (size_t)N_EDGES * 16;
  float* agg2    = (float*)(ws + off); off += (size_t)N_NODES * 256 * 4;
  ushort_t* h0h  = (ushort_t*)(ws + off); off += (size_t)N_NODES * HDIM * 2;
  ushort_t* h1h  = (ushort_t*)(ws + off); off += (size_t)N_NODES * HDIM * 2;
  ushort_t* Wh1  = (ushort_t*)(ws + off); off += (size_t)NREL * NBLK * 64 * 2;
  ushort_t* Wh2  = (ushort_t*)(ws + off); off += (size_t)NREL * NBLK * 128 * 2;
  float* agg1 = out;  // agg1 lives in d_out (dead before node_layer2f writes)

  // ---- CSR build + f16 conversions ----
  hipMemsetAsync(deg, 0, (size_t)N_NODES * 4, stream);
  hipMemsetAsync(cursor, 0, (size_t)N_NODES * 4, stream);
  hist_deg<<<(N_EDGES + 255) / 256, 256, 0, stream>>>(dst, deg);
  conv_w1<<<(NREL * NBLK * 64 + 255) / 256, 256, 0, stream>>>(W1, Wh1);
  conv_w2<<<(NREL * NBLK * 128 + 255) / 256, 256, 0, stream>>>(W2, Wh2);
  scan_offsets<<<1, 1024, 0, stream>>>(deg, offsets);
  calc_ranges<<<(NW_AGG + 256) / 256, 256, 0, stream>>>(offsets, ranges);
  scatter_rec<<<(N_EDGES + 255) / 256, 256, 0, stream>>>(src, dst, etype, norm,
                                                         offsets, cursor, rec);
  conv_h0<<<(N_NODES * HDIM + 255) / 256, 256, 0, stream>>>(node_ids, emb, h0h);

  // ---- layer 1 ----
  agg_layer1<<<NW_AGG / 4, 256, 0, stream>>>(rec, offsets, ranges, h0h, Wh1, agg1);
  node_layer1<<<1024, 256, 0, stream>>>(h0h, loop1, agg1, b1, h1h);

  // ---- layer 2 ----
  agg_layer2<<<NW_AGG / 4, 256, 0, stream>>>(rec, offsets, ranges, h1h, Wh2, agg2);
  node_layer2f<<<512, 256, 0, stream>>>(h1h, loop2, agg2, b2, eps, out);
}